// Round 2
// baseline (96.849 us; speedup 1.0000x reference)
//
#include <hip/hip_runtime.h>
#include <hip/hip_bf16.h>

#define NPART 8192
#define NCT 4
#define TPB 256

// dtype-generic scalar load: bf16 (upcast) or fp32
__device__ __forceinline__ float loadf(const void* p, int idx, bool bf) {
    if (bf) {
        unsigned int u = ((const unsigned short*)p)[idx];
        return __uint_as_float(u << 16);
    }
    return ((const float*)p)[idx];
}

__global__ void zero_kernel(float* acc) { *acc = 0.0f; }

__global__ __launch_bounds__(TPB) void pair_kernel(const void* __restrict__ eps,
                                                   const void* __restrict__ alp,
                                                   const void* __restrict__ ct,
                                                   const void* __restrict__ rad,
                                                   const void* __restrict__ pos,
                                                   float* __restrict__ acc_out)
{
    __shared__ float4 sp[TPB];
    __shared__ int ssp[TPB];
    __shared__ float stab[32];
    __shared__ float red[TPB / 64];

    const int t = threadIdx.x;

    // --- dtype detection (uniform): fp32 one-hot words have low16 == 0 ---
    unsigned int w = ((const unsigned int*)ct)[t & 63];
    const bool bf = (__ballot((w & 0xFFFFu) != 0) != 0ull);

    // --- species tables: symmetrize + sigmoid*vmax + vmin ---
    if (t < 16) {
        int a = t >> 2, b = t & 3;
        float me = (a == b) ? loadf(eps, a * NCT + a, bf)
                            : 0.5f * (loadf(eps, a * NCT + b, bf) + loadf(eps, b * NCT + a, bf));
        float ma = (a == b) ? loadf(alp, a * NCT + a, bf)
                            : 0.5f * (loadf(alp, a * NCT + b, bf) + loadf(alp, b * NCT + a, bf));
        stab[t]      = 5.0f / (1.0f + __expf(-me)) + 1.0f;   // EPS_MAX, EPS_MIN
        stab[16 + t] = 3.0f / (1.0f + __expf(-ma)) + 1.0f;   // ALPHA_MAX, ALPHA_MIN
    }

    // --- stage j-tile ---
    const int j0 = blockIdx.y * TPB;
    {
        int j = j0 + t;
        float4 pj;
        pj.x = loadf(pos, j * 3 + 0, bf);
        pj.y = loadf(pos, j * 3 + 1, bf);
        pj.z = loadf(pos, j * 3 + 2, bf);
        pj.w = loadf(rad, j, bf);
        sp[t] = pj;
        int sj = -1;
#pragma unroll
        for (int c = 0; c < NCT; ++c)
            if (loadf(ct, j * NCT + c, bf) > 0.5f) sj = c;
        ssp[t] = sj;
    }

    // --- own i row ---
    const int i = blockIdx.x * TPB + t;
    float4 pi;
    pi.x = loadf(pos, i * 3 + 0, bf);
    pi.y = loadf(pos, i * 3 + 1, bf);
    pi.z = loadf(pos, i * 3 + 2, bf);
    pi.w = loadf(rad, i, bf);
    int si = -1;
#pragma unroll
    for (int c = 0; c < NCT; ++c)
        if (loadf(ct, i * NCT + c, bf) > 0.5f) si = c;

    __syncthreads();

    constexpr float RC2 = 4.0f;            // R_CUTOFF^2
    constexpr float RO2 = 1.7f * 1.7f;     // R_ONSET^2
    constexpr float C1  = RC2 - 3.0f * RO2;
    const float INV_D = 1.0f / ((RC2 - RO2) * (RC2 - RO2) * (RC2 - RO2));

    float acc = 0.0f;
    if (si >= 0) {
#pragma unroll 4
        for (int jj = 0; jj < TPB; ++jj) {
            float4 pj = sp[jj];
            float dx = pi.x - pj.x;
            float dy = pi.y - pj.y;
            float dz = pi.z - pj.z;
            float dr2 = fmaf(dx, dx, fmaf(dy, dy, dz * dz));
            if (dr2 < RC2) {
                int j = j0 + jj;
                int sj = ssp[jj];
                if (j != i && sj >= 0) {
                    float e = stab[(si << 2) | sj];
                    float a = stab[16 + ((si << 2) | sj)];
                    float dr = sqrtf(dr2);
                    float ex = __expf(-a * (dr - (pi.w + pj.w)));
                    float om = 1.0f - ex;
                    float u = fmaf(e * om, om, -e);          // eps*(1-ex)^2 - eps
                    float smooth = 1.0f;
                    if (dr2 >= RO2) {
                        float d = RC2 - dr2;
                        smooth = d * d * fmaf(2.0f, dr2, C1) * INV_D;
                    }
                    acc += u * smooth;
                }
            }
        }
    }

    // wave(64) shuffle reduction -> LDS -> one atomic per block
#pragma unroll
    for (int off = 32; off > 0; off >>= 1) acc += __shfl_down(acc, off, 64);
    int lane = t & 63, wv = t >> 6;
    if (lane == 0) red[wv] = acc;
    __syncthreads();
    if (t == 0) {
        float s = red[0] + red[1] + red[2] + red[3];
        atomicAdd(acc_out, 0.5f * s);
    }
}

__global__ void finalize_kernel(const float* __restrict__ acc,
                                const void* __restrict__ ct,
                                void* __restrict__ out)
{
    bool bf = false;
    const unsigned int* cw = (const unsigned int*)ct;
    for (int k = 0; k < 64; ++k) bf |= (cw[k] & 0xFFFFu) != 0;
    float v = acc[0];
    if (bf) ((__hip_bfloat16*)out)[0] = __float2bfloat16(v);
    else    ((float*)out)[0] = v;
}

extern "C" void kernel_launch(void* const* d_in, const int* in_sizes, int n_in,
                              void* d_out, int out_size, void* d_ws, size_t ws_size,
                              hipStream_t stream)
{
    // Map inputs by element count (robust to ordering); eps/alpha both 16 -> keep order.
    const void* eps = nullptr; const void* alp = nullptr;
    const void* ct = nullptr;  const void* rad = nullptr; const void* pos = nullptr;
    int nsmall = 0;
    for (int k = 0; k < n_in; ++k) {
        int s = in_sizes[k];
        if (s == NCT * NCT)        { if (nsmall++ == 0) eps = d_in[k]; else alp = d_in[k]; }
        else if (s == NPART * NCT) ct  = d_in[k];
        else if (s == NPART)       rad = d_in[k];
        else if (s == NPART * 3)   pos = d_in[k];
    }
    if (!eps || !alp || !ct || !rad || !pos) {  // fallback: dict order
        eps = d_in[0]; alp = d_in[1]; ct = d_in[2]; rad = d_in[3]; pos = d_in[4];
    }

    float* acc = (float*)d_ws;   // 4 bytes of workspace only

    zero_kernel<<<1, 1, 0, stream>>>(acc);
    dim3 grid(NPART / TPB, NPART / TPB);
    pair_kernel<<<grid, TPB, 0, stream>>>(eps, alp, ct, rad, pos, acc);
    finalize_kernel<<<1, 1, 0, stream>>>(acc, ct, d_out);
}

// Round 3
// 89.995 us; speedup vs baseline: 1.0762x; 1.0762x over previous
//
#include <hip/hip_runtime.h>
#include <hip/hip_bf16.h>

#define NPART 8192
#define NCT 4
#define TPB 256
#define NTILE (NPART / TPB)                 // 32
#define NBLK (NTILE * (NTILE + 1) / 2)      // 528 triangular tiles

// dtype-generic scalar load: bf16 (upcast) or fp32
__device__ __forceinline__ float loadf(const void* p, int idx, bool bf) {
    if (bf) {
        unsigned int u = ((const unsigned short*)p)[idx];
        return __uint_as_float(u << 16);
    }
    return ((const float*)p)[idx];
}

__global__ __launch_bounds__(TPB) void pair_kernel(const void* __restrict__ eps,
                                                   const void* __restrict__ alp,
                                                   const void* __restrict__ ct,
                                                   const void* __restrict__ rad,
                                                   const void* __restrict__ pos,
                                                   float* __restrict__ partials)
{
    __shared__ float4 sp[TPB];
    __shared__ int ssp[TPB];
    __shared__ float stab[32];
    __shared__ float red[TPB / 64];

    const int t = threadIdx.x;

    // --- dtype detection (wave-uniform): fp32 one-hot words have low16 == 0 ---
    unsigned int w = ((const unsigned int*)ct)[t & 63];
    const bool bf = (__ballot((w & 0xFFFFu) != 0) != 0ull);

    // --- triangular tile decode: linear b -> (bx <= by) ---
    const int b = blockIdx.x;
    int by = (int)((sqrtf(8.0f * (float)b + 1.0f) - 1.0f) * 0.5f);
    while ((by + 1) * (by + 2) / 2 <= b) ++by;
    while (by * (by + 1) / 2 > b) --by;
    const int bx = b - by * (by + 1) / 2;
    const bool diag = (bx == by);

    // --- species tables: symmetrize + sigmoid*vmax + vmin ---
    if (t < 16) {
        int a = t >> 2, c = t & 3;
        float me = (a == c) ? loadf(eps, a * NCT + a, bf)
                            : 0.5f * (loadf(eps, a * NCT + c, bf) + loadf(eps, c * NCT + a, bf));
        float ma = (a == c) ? loadf(alp, a * NCT + a, bf)
                            : 0.5f * (loadf(alp, a * NCT + c, bf) + loadf(alp, c * NCT + a, bf));
        stab[t]      = 5.0f / (1.0f + __expf(-me)) + 1.0f;   // EPS_MAX..EPS_MIN
        stab[16 + t] = 3.0f / (1.0f + __expf(-ma)) + 1.0f;   // ALPHA_MAX..ALPHA_MIN
    }

    // --- stage j-tile (from by) ---
    const int j0 = by * TPB;
    {
        int j = j0 + t;
        float4 pj;
        pj.x = loadf(pos, j * 3 + 0, bf);
        pj.y = loadf(pos, j * 3 + 1, bf);
        pj.z = loadf(pos, j * 3 + 2, bf);
        pj.w = loadf(rad, j, bf);
        sp[t] = pj;
        int sj = -1;
#pragma unroll
        for (int c = 0; c < NCT; ++c)
            if (loadf(ct, j * NCT + c, bf) > 0.5f) sj = c;
        ssp[t] = sj;
    }

    // --- own i row (from bx) ---
    const int i = bx * TPB + t;
    float4 pi;
    pi.x = loadf(pos, i * 3 + 0, bf);
    pi.y = loadf(pos, i * 3 + 1, bf);
    pi.z = loadf(pos, i * 3 + 2, bf);
    pi.w = loadf(rad, i, bf);
    int si = -1;
#pragma unroll
    for (int c = 0; c < NCT; ++c)
        if (loadf(ct, i * NCT + c, bf) > 0.5f) si = c;

    __syncthreads();

    constexpr float RC2 = 4.0f;            // R_CUTOFF^2
    constexpr float RO2 = 1.7f * 1.7f;     // R_ONSET^2
    constexpr float C1  = RC2 - 3.0f * RO2;
    const float INV_D = 1.0f / ((RC2 - RO2) * (RC2 - RO2) * (RC2 - RO2));

    float acc = 0.0f;
    if (si >= 0) {
#pragma unroll 8
        for (int jj = 0; jj < TPB; ++jj) {
            float4 pj = sp[jj];
            float dx = pi.x - pj.x;
            float dy = pi.y - pj.y;
            float dz = pi.z - pj.z;
            float dr2 = fmaf(dx, dx, fmaf(dy, dy, dz * dz));
            if (dr2 < RC2) {                       // rare (~3% of wave-iters hit)
                int j = j0 + jj;
                int sj = ssp[jj];
                if (j != i && sj >= 0) {
                    float e = stab[(si << 2) | sj];
                    float a = stab[16 + ((si << 2) | sj)];
                    float dr = sqrtf(dr2);
                    float ex = __expf(-a * (dr - (pi.w + pj.w)));
                    float om = 1.0f - ex;
                    float u = fmaf(e * om, om, -e);          // eps*(1-ex)^2 - eps
                    float smooth = 1.0f;
                    if (dr2 >= RO2) {
                        float d = RC2 - dr2;
                        smooth = d * d * fmaf(2.0f, dr2, C1) * INV_D;
                    }
                    acc += u * smooth;
                }
            }
        }
    }

    // tile weight: off-diag counted once (i<j covered exactly), diag 0.5 * sum_{i!=j}
    acc *= diag ? 0.5f : 1.0f;

    // wave(64) shuffle reduction -> LDS -> per-block partial (no atomics, no pre-zero)
#pragma unroll
    for (int off = 32; off > 0; off >>= 1) acc += __shfl_down(acc, off, 64);
    int lane = t & 63, wv = t >> 6;
    if (lane == 0) red[wv] = acc;
    __syncthreads();
    if (t == 0) partials[b] = red[0] + red[1] + red[2] + red[3];
}

__global__ __launch_bounds__(TPB) void finalize_kernel(const float* __restrict__ partials,
                                                       const void* __restrict__ ct,
                                                       void* __restrict__ out)
{
    __shared__ float red[TPB / 64];
    const int t = threadIdx.x;

    unsigned int w = ((const unsigned int*)ct)[t & 63];
    const bool bf = (__ballot((w & 0xFFFFu) != 0) != 0ull);

    float s = 0.0f;
    for (int k = t; k < NBLK; k += TPB) s += partials[k];
#pragma unroll
    for (int off = 32; off > 0; off >>= 1) s += __shfl_down(s, off, 64);
    int lane = t & 63, wv = t >> 6;
    if (lane == 0) red[wv] = s;
    __syncthreads();
    if (t == 0) {
        float v = red[0] + red[1] + red[2] + red[3];
        if (bf) ((__hip_bfloat16*)out)[0] = __float2bfloat16(v);
        else    ((float*)out)[0] = v;
    }
}

extern "C" void kernel_launch(void* const* d_in, const int* in_sizes, int n_in,
                              void* d_out, int out_size, void* d_ws, size_t ws_size,
                              hipStream_t stream)
{
    // Map inputs by element count (robust to ordering); eps/alpha both 16 -> keep order.
    const void* eps = nullptr; const void* alp = nullptr;
    const void* ct = nullptr;  const void* rad = nullptr; const void* pos = nullptr;
    int nsmall = 0;
    for (int k = 0; k < n_in; ++k) {
        int s = in_sizes[k];
        if (s == NCT * NCT)        { if (nsmall++ == 0) eps = d_in[k]; else alp = d_in[k]; }
        else if (s == NPART * NCT) ct  = d_in[k];
        else if (s == NPART)       rad = d_in[k];
        else if (s == NPART * 3)   pos = d_in[k];
    }
    if (!eps || !alp || !ct || !rad || !pos) {
        eps = d_in[0]; alp = d_in[1]; ct = d_in[2]; rad = d_in[3]; pos = d_in[4];
    }

    float* partials = (float*)d_ws;  // NBLK floats; overwritten every call, no pre-zero needed

    pair_kernel<<<NBLK, TPB, 0, stream>>>(eps, alp, ct, rad, pos, partials);
    finalize_kernel<<<1, TPB, 0, stream>>>(partials, ct, d_out);
}